// Round 7
// baseline (231.397 us; speedup 1.0000x reference)
//
#include <hip/hip_runtime.h>
#include <math.h>

#define S 8192
#define E 64
#define CAP 256
static const long long NOUT = (long long)S * E * CAP;  // 134,217,728 elems per output
static const long long NQH  = NOUT / 4;                // 33,554,432 float4s per output

typedef float f32x4 __attribute__((ext_vector_type(4)));
typedef int   i32x4 __attribute__((ext_vector_type(4)));

// ---------------------------------------------------------------------------
// Kernel A: per-row fp32 softmax + top-1/top-2 selection.
// One wave (64 lanes) per row; lane == expert id. 4 rows per block.
// Writes idx1/idx2 (for the rank kernel) and the v1/v2 fields of the
// per-token patch table.
// ---------------------------------------------------------------------------
__global__ void softmax_top2(const float* __restrict__ in,
                             int* __restrict__ idx1, int* __restrict__ idx2,
                             i32x4* __restrict__ table) {
    const int lane = threadIdx.x;          // 0..63, == expert id
    const int row  = blockIdx.x * 4 + threadIdx.y;

    float x = in[row * E + lane];

    float mx = x;
    #pragma unroll
    for (int o = 32; o > 0; o >>= 1) mx = fmaxf(mx, __shfl_xor(mx, o));

    float p = __expf(x - mx);
    float sum = p;
    #pragma unroll
    for (int o = 32; o > 0; o >>= 1) sum += __shfl_xor(sum, o);
    float prob = p / sum;

    // argmax on x (monotonic w.r.t. softmax), first-index tie-break
    float v = x; int idx = lane;
    #pragma unroll
    for (int o = 32; o > 0; o >>= 1) {
        float ov = __shfl_xor(v, o);
        int   oi = __shfl_xor(idx, o);
        if (ov > v || (ov == v && oi < idx)) { v = ov; idx = oi; }
    }
    const int i1 = idx;

    float x2 = (lane == i1) ? -INFINITY : x;
    v = x2; idx = lane;
    #pragma unroll
    for (int o = 32; o > 0; o >>= 1) {
        float ov = __shfl_xor(v, o);
        int   oi = __shfl_xor(idx, o);
        if (ov > v || (ov == v && oi < idx)) { v = ov; idx = oi; }
    }
    const int i2 = idx;

    const float pw1 = __shfl(prob, i1);
    const float pw2 = __shfl(prob, i2);

    if (lane == 0) {
        idx1[row] = i1;
        idx2[row] = i2;
        int* tp = (int*)&table[row];
        tp[1] = __float_as_int(pw1);       // v1 field
        tp[3] = __float_as_int(pw2);       // v2 field
    }
}

// ---------------------------------------------------------------------------
// Kernel B: per-expert exclusive ranks via ballot-prefix (4 waves / expert
// block), writing the p1/p2 fields of the patch table:
//   p = expert*CAP + rank  if rank < CAP else -1   (element pos within row)
// Token t's p1 is written by exactly one block (expert idx1[t]); p2 likewise.
// ---------------------------------------------------------------------------
__global__ __launch_bounds__(256) void rank_pack(
        const int* __restrict__ idx1, const int* __restrict__ idx2,
        i32x4* __restrict__ table) {
    const int e    = blockIdx.x;
    const int lane = threadIdx.x & 63;
    const int w    = threadIdx.x >> 6;        // wave 0..3
    const int seg  = S / 4;                   // 2048 tokens per wave
    const int t0w  = w * seg;
    const unsigned long long below = (1ULL << lane) - 1ULL;

    __shared__ int c1s[4], c2s[4];

    int c1 = 0, c2 = 0;
    #pragma unroll 4
    for (int t0 = t0w; t0 < t0w + seg; t0 += 64) {
        const int t = t0 + lane;
        c1 += __popcll(__ballot(idx1[t] == e));
        c2 += __popcll(__ballot(idx2[t] == e));
    }
    if (lane == 0) { c1s[w] = c1; c2s[w] = c2; }
    __syncthreads();

    const int tot1 = c1s[0] + c1s[1] + c1s[2] + c1s[3];
    int off1 = 0, off2 = tot1;                 // rank2 offset by total top1 count
    for (int k = 0; k < w; ++k) { off1 += c1s[k]; off2 += c2s[k]; }

    int base = off1;
    #pragma unroll 4
    for (int t0 = t0w; t0 < t0w + seg; t0 += 64) {
        const int t = t0 + lane;
        const unsigned long long m = __ballot(idx1[t] == e);
        if (idx1[t] == e) {
            const int r = base + __popcll(m & below);
            ((int*)&table[t])[0] = (r < CAP) ? (e * CAP + r) : -1;
        }
        base += __popcll(m);
    }
    base = off2;
    #pragma unroll 4
    for (int t0 = t0w; t0 < t0w + seg; t0 += 64) {
        const int t = t0 + lane;
        const unsigned long long m = __ballot(idx2[t] == e);
        if (idx2[t] == e) {
            const int r = base + __popcll(m & below);
            ((int*)&table[t])[2] = (r < CAP) ? (e * CAP + r) : -1;
        }
        base += __popcll(m);
    }
}

// ---------------------------------------------------------------------------
// Kernel C: fused flat zero-fill + in-register patch. Exact rocclr-fill
// shape: ONE dwordx4 store per thread, flat grid, no loop. Each block covers
// 1024 consecutive elements (1/16 of one token row) => the table entry is
// block-uniform (one broadcast 16-B load).
// ---------------------------------------------------------------------------
__global__ __launch_bounds__(256) void fill_patch(
        const i32x4* __restrict__ table, f32x4* __restrict__ out) {
    const long long i = (long long)blockIdx.x * 256 + threadIdx.x;
    const bool mask_half = (i >= NQH);         // uniform per block
    const long long j = mask_half ? i - NQH : i;
    const int t  = (int)(j >> 12);             // token (4096 float4s per row)
    const int rq = ((int)j & 4095) << 2;       // first element pos of this float4
    const i32x4 te = table[t];

    float v1 = __int_as_float(te.y);
    float v2 = __int_as_float(te.w);
    if (mask_half) {
        v1 = (v1 != 0.0f) ? 1.0f : 0.0f;
        v2 = (v2 != 0.0f) ? 1.0f : 0.0f;
    }

    f32x4 v = {0.f, 0.f, 0.f, 0.f};
    #pragma unroll
    for (int k = 0; k < 4; ++k) {
        if (te.x == rq + k) v[k] = v1;
        if (te.z == rq + k) v[k] = v2;
    }
    out[i] = v;
}

extern "C" void kernel_launch(void* const* d_in, const int* in_sizes, int n_in,
                              void* d_out, int out_size, void* d_ws, size_t ws_size,
                              hipStream_t stream) {
    const float* in = (const float*)d_in[0];
    float* out = (float*)d_out;

    // workspace layout: idx1[8192], idx2[8192], table[8192 x int4]
    int*   idx1  = (int*)d_ws;
    int*   idx2  = idx1 + S;
    i32x4* table = (i32x4*)(idx2 + S);         // 64 KB offset -> 16B aligned

    softmax_top2<<<S / 4, dim3(64, 4), 0, stream>>>(in, idx1, idx2, table);
    rank_pack<<<E, 256, 0, stream>>>(idx1, idx2, table);
    fill_patch<<<(int)(2 * NQH / 256), 256, 0, stream>>>(table, (f32x4*)out);
}

// Round 8
// 193.291 us; speedup vs baseline: 1.1971x; 1.1971x over previous
//
#include <hip/hip_runtime.h>
#include <math.h>

#define S 8192
#define E 64
#define CAP 256
static const long long NOUT = (long long)S * E * CAP;  // 134,217,728 elems per output
static const long long NQ   = (2 * NOUT) / 4;          // 67,108,864 float4s total

typedef float f32x4 __attribute__((ext_vector_type(4)));

// ---------------------------------------------------------------------------
// Kernel A: per-row fp32 softmax + top-1/top-2 selection.
// One wave (64 lanes) per row; lane == expert id. 4 rows per block.
// Packs i1|i2<<16 into one word to halve the rank kernel's load traffic.
// ---------------------------------------------------------------------------
__global__ void softmax_top2(const float* __restrict__ in,
                             int* __restrict__ pk,
                             float* __restrict__ w1, float* __restrict__ w2) {
    const int lane = threadIdx.x;          // 0..63, == expert id
    const int row  = blockIdx.x * 4 + threadIdx.y;

    float x = in[row * E + lane];

    float mx = x;
    #pragma unroll
    for (int o = 32; o > 0; o >>= 1) mx = fmaxf(mx, __shfl_xor(mx, o));

    float p = __expf(x - mx);
    float sum = p;
    #pragma unroll
    for (int o = 32; o > 0; o >>= 1) sum += __shfl_xor(sum, o);
    float prob = p / sum;

    // argmax on x (monotonic w.r.t. softmax), first-index tie-break
    float v = x; int idx = lane;
    #pragma unroll
    for (int o = 32; o > 0; o >>= 1) {
        float ov = __shfl_xor(v, o);
        int   oi = __shfl_xor(idx, o);
        if (ov > v || (ov == v && oi < idx)) { v = ov; idx = oi; }
    }
    const int i1 = idx;

    float x2 = (lane == i1) ? -INFINITY : x;
    v = x2; idx = lane;
    #pragma unroll
    for (int o = 32; o > 0; o >>= 1) {
        float ov = __shfl_xor(v, o);
        int   oi = __shfl_xor(idx, o);
        if (ov > v || (ov == v && oi < idx)) { v = ov; idx = oi; }
    }
    const int i2 = idx;

    const float pw1 = __shfl(prob, i1);
    const float pw2 = __shfl(prob, i2);

    if (lane == 0) {
        pk[row] = i1 | (i2 << 16);
        w1[row] = pw1;
        w2[row] = pw2;
    }
}

// ---------------------------------------------------------------------------
// Kernel B: flat zero-fill, rocclr-fillBuffer shape: ONE dwordx4 store per
// thread, flat grid, no loop. (Measured 5.9 TB/s; looped variants 4.3.)
// ---------------------------------------------------------------------------
__global__ __launch_bounds__(256) void fill_zero(f32x4* __restrict__ out) {
    const size_t i = (size_t)blockIdx.x * 256 + threadIdx.x;
    const f32x4 z = {0.f, 0.f, 0.f, 0.f};
    out[i] = z;
}

// ---------------------------------------------------------------------------
// Kernel C: fused rank + scatter, 8 waves per expert block (512 thr).
// Wave w owns tokens [w*1024, (w+1)*1024). Phase 1: per-wave match counts.
// Phase 2 (after LDS exchange): exclusive base per wave, ballot-prefix
// ranks, direct scatter of the <=2 entries per matched token.
// ---------------------------------------------------------------------------
__global__ __launch_bounds__(512) void rank_scatter(
        const int* __restrict__ pk,
        const float* __restrict__ w1, const float* __restrict__ w2,
        float* __restrict__ out) {
    const int e    = blockIdx.x;
    const int lane = threadIdx.x & 63;
    const int w    = threadIdx.x >> 6;        // wave 0..7
    const int seg  = S / 8;                   // 1024 tokens per wave
    const int t0w  = w * seg;
    const unsigned long long below = (1ULL << lane) - 1ULL;

    __shared__ int c1s[8], c2s[8];

    // phase 1: per-wave match counts (1 packed load per iter)
    int c1 = 0, c2 = 0;
    #pragma unroll 4
    for (int t0 = t0w; t0 < t0w + seg; t0 += 64) {
        const int p = pk[t0 + lane];
        c1 += __popcll(__ballot((p & 0xffff) == e));
        c2 += __popcll(__ballot((p >> 16) == e));
    }
    if (lane == 0) { c1s[w] = c1; c2s[w] = c2; }
    __syncthreads();

    int tot1 = 0;
    #pragma unroll
    for (int k = 0; k < 8; ++k) tot1 += c1s[k];
    int off1 = 0, off2 = tot1;                 // rank2 offset by total top1 count
    for (int k = 0; k < w; ++k) { off1 += c1s[k]; off2 += c2s[k]; }

    // phase 2: ballot-prefix ranks + direct scatter
    int base = off1;
    #pragma unroll 4
    for (int t0 = t0w; t0 < t0w + seg; t0 += 64) {
        const int t = t0 + lane;
        const bool hit = (pk[t] & 0xffff) == e;
        const unsigned long long m = __ballot(hit);
        if (hit) {
            const int r = base + __popcll(m & below);
            if (r < CAP) {
                const float v = w1[t];
                const long long off = (long long)t * (E * CAP) + e * CAP + r;
                out[off]        = v;
                out[NOUT + off] = (v != 0.0f) ? 1.0f : 0.0f;
            }
        }
        base += __popcll(m);
    }
    base = off2;
    #pragma unroll 4
    for (int t0 = t0w; t0 < t0w + seg; t0 += 64) {
        const int t = t0 + lane;
        const bool hit = (pk[t] >> 16) == e;
        const unsigned long long m = __ballot(hit);
        if (hit) {
            const int r = base + __popcll(m & below);
            if (r < CAP) {
                const float v = w2[t];
                const long long off = (long long)t * (E * CAP) + e * CAP + r;
                out[off]        = v;
                out[NOUT + off] = (v != 0.0f) ? 1.0f : 0.0f;
            }
        }
        base += __popcll(m);
    }
}

extern "C" void kernel_launch(void* const* d_in, const int* in_sizes, int n_in,
                              void* d_out, int out_size, void* d_ws, size_t ws_size,
                              hipStream_t stream) {
    const float* in = (const float*)d_in[0];
    float* out = (float*)d_out;

    // workspace layout (8192 each): pk, w1, w2
    int*   pk = (int*)d_ws;
    float* w1 = (float*)(pk + S);
    float* w2 = w1 + S;

    softmax_top2<<<S / 4, dim3(64, 4), 0, stream>>>(in, pk, w1, w2);
    fill_zero<<<(int)(NQ / 256), 256, 0, stream>>>((f32x4*)out);
    rank_scatter<<<E, 512, 0, stream>>>(pk, w1, w2, out);
}